// Round 6
// baseline (118.351 us; speedup 1.0000x reference)
//
#include <hip/hip_runtime.h>
#include <hip/hip_bf16.h>

// GMM NLL: N=524288 rows, P=16, G=8.
// R6: R5's 32x32x16 MFMA algorithm, but with ZERO private arrays/unions.
//   Diagnosis across R1-R5: VGPR_Count 32-52 while >=32 floats of per-thread
//   array state are live => compiler put xt[]/unions in SCRATCH. Scratch
//   loads at L2 latency on every use explain the universal 44-60us plateau,
//   the all-pipes-idle counters, and why FETCH/WRITE never showed it.
//   Fix: every per-thread array -> named scalars via macros; unions ->
//   __builtin_bit_cast; prep state -> LDS only.

#define P 16
#define G 8

typedef short bf16x8 __attribute__((ext_vector_type(8)));
typedef unsigned u32x4v __attribute__((ext_vector_type(4)));
typedef float f32x16 __attribute__((ext_vector_type(16)));

__device__ __forceinline__ unsigned short f2bf(float f) {
    unsigned u = __builtin_bit_cast(unsigned, f);
    return (unsigned short)((u + 0x7FFFu + ((u >> 16) & 1u)) >> 16);  // RNE
}

// ws float-offset layout:
//   [0,1024)    A-frags: ushort[4 pairs][64 lanes][8]  (4 KB)
//   [1024,1280) u-frags: uint[4 pairs][64 lanes] (low16 = bf16(-u) for lane<32 else 0)
//   [1280,1288) lcoef[G] = log softmax(w) + lead - 0.5*logdet
//   [1288,...)  lam[P], lam-1[P], 1/lam[P]
#define UFRAG_F 1024
#define WS_LC   1280
#define WS_LAM  1288
#define WS_LM1  1304
#define WS_RL   1320

__global__ __launch_bounds__(128) void gmm_prep(const float* __restrict__ lambdas,
                                                const float* __restrict__ mus,
                                                const float* __restrict__ sigmas,
                                                const float* __restrict__ w,
                                                float* __restrict__ ws,
                                                float* __restrict__ out) {
    __shared__ float Lsh[G][P][P];
    __shared__ float Vsh[G][P][P];
    __shared__ float u_sh[G][P];
    __shared__ float ldet[G];
    const int tid = threadIdx.x;
    const int g = tid >> 4;
    const int r = tid & 15;

    // Cholesky, column by column; all state in LDS (no private arrays).
    for (int j = 0; j < P; ++j) {
        float s = sigmas[g * P * P + r * P + j];
        for (int k = 0; k < j; ++k) s -= Lsh[g][r][k] * Lsh[g][j][k];
        if (r == j) Lsh[g][j][j] = sqrtf(s);
        __syncthreads();
        if (r > j) Lsh[g][r][j] = s / Lsh[g][j][j];
        __syncthreads();
    }

    if (r == 0) {
        float ld = 0.f;
        for (int j = 0; j < P; ++j) ld += __logf(Lsh[g][j][j]);
        ldet[g] = 2.0f * ld;
    }

    // invert L: thread r computes column r of V = L^{-1} directly into Vsh.
    // Column entries above the diagonal are zero; own-column reads need no sync.
    for (int i = 0; i < P; ++i) {
        float s = 0.f;
        for (int k = r; k < i; ++k) s += Lsh[g][i][k] * Vsh[g][k][r];
        const float rii = 1.0f / Lsh[g][i][i];
        Vsh[g][i][r] = (i == r) ? rii : ((i < r) ? 0.f : -s * rii);
    }
    __syncthreads();

    // u_g[r] = (V_g mu_g)[r]
    {
        float u = 0.f;
        for (int j = 0; j < P; ++j) u = fmaf(Vsh[g][r][j], mus[g * P + j], u);
        u_sh[g][r] = u;
    }
    __syncthreads();

    // Fragment tables for mfma_f32_32x32x16_bf16:
    //   A[m][k], m=lane&31, k=(lane>>5)*8+j. Pair p rows: m<16 -> grp 2p, else 2p+1.
    unsigned short* ws16 = (unsigned short*)ws;
    unsigned* wsu32 = (unsigned*)(ws + UFRAG_F);
    for (int pid = tid; pid < 256; pid += 128) {
        const int p = pid >> 6, ln = pid & 63;
        const int m = ln & 31, half = ln >> 5;
        const int grp = 2 * p + (m >> 4), i = m & 15;
        unsigned short* dst = ws16 + (p * 64 + ln) * 8;
        for (int j = 0; j < 8; ++j) dst[j] = f2bf(Vsh[grp][i][half * 8 + j]);
        wsu32[p * 64 + ln] = (half == 0) ? (unsigned)f2bf(-u_sh[grp][i]) : 0u;
    }

    if (tid == 0) {
        float wm = w[0];
        for (int k = 1; k < G; ++k) wm = fmaxf(wm, w[k]);
        float s = 0.f;
        for (int k = 0; k < G; ++k) s += __expf(w[k] - wm);
        const float lse = wm + __logf(s);
        const float lead = -14.7030165f; // -0.5 * 16 * ln(2*pi)
        for (int k = 0; k < G; ++k)
            ws[WS_LC + k] = (w[k] - lse) + lead - 0.5f * ldet[k];
        out[0] = 0.f;
    }
    if (tid < P) {
        float lam = lambdas[tid];
        ws[WS_LAM + tid] = lam;
        ws[WS_LM1 + tid] = lam - 1.0f;
        ws[WS_RL  + tid] = 1.0f / lam;
    }
}

__global__ __launch_bounds__(256, 4) void gmm_main(const float* __restrict__ X,
                                                   const float* __restrict__ ws,
                                                   float* __restrict__ out,
                                                   int nrows) {
    __shared__ u32x4v sxt4[512];   // 8 frag-slots x 64 entries x 16B = 8 KB
    __shared__ float red[4];

    const int tid  = threadIdx.x;
    const int lane = tid & 63;
    const int wid  = tid >> 6;
    const unsigned short* ws16 = (const unsigned short*)ws;
    const unsigned* wsu32 = (const unsigned*)(ws + UFRAG_F);

    // resident fragments: 4 named A-vectors + 4 named u-vectors
    const bf16x8 av0 = *(const bf16x8*)(ws16 + (0 * 64 + lane) * 8);
    const bf16x8 av1 = *(const bf16x8*)(ws16 + (1 * 64 + lane) * 8);
    const bf16x8 av2 = *(const bf16x8*)(ws16 + (2 * 64 + lane) * 8);
    const bf16x8 av3 = *(const bf16x8*)(ws16 + (3 * 64 + lane) * 8);
    bf16x8 au0 = {0,0,0,0,0,0,0,0}; au0[0] = (short)wsu32[0 * 64 + lane];
    bf16x8 au1 = {0,0,0,0,0,0,0,0}; au1[0] = (short)wsu32[1 * 64 + lane];
    bf16x8 au2 = {0,0,0,0,0,0,0,0}; au2[0] = (short)wsu32[2 * 64 + lane];
    bf16x8 au3 = {0,0,0,0,0,0,0,0}; au3[0] = (short)wsu32[3 * 64 + lane];

    const int row = blockIdx.x * 256 + tid;
    const int rc = row < nrows ? row : nrows - 1;
    const float4* Xv = (const float4*)(X + (size_t)rc * P);
    const float4 A0 = Xv[0], A1 = Xv[1], A2 = Xv[2], A3 = Xv[3];

    float jac = 0.f;
#define XTP(i, xv_) \
    const float ln##i = __logf(xv_); \
    const float xt##i = (__expf(ws[WS_LAM + i] * ln##i) - 1.0f) * ws[WS_RL + i]; \
    jac = fmaf(ln##i, ws[WS_LM1 + i], jac);
    XTP(0, A0.x)  XTP(1, A0.y)  XTP(2, A0.z)  XTP(3, A0.w)
    XTP(4, A1.x)  XTP(5, A1.y)  XTP(6, A1.z)  XTP(7, A1.w)
    XTP(8, A2.x)  XTP(9, A2.y)  XTP(10, A2.z) XTP(11, A2.w)
    XTP(12, A3.x) XTP(13, A3.y) XTP(14, A3.z) XTP(15, A3.w)
#undef XTP

    // pack xt -> bf16 pairs (named words, no arrays/unions)
#define PK(h_, a_, b_) const unsigned w##h_ = (unsigned)f2bf(xt##a_) | ((unsigned)f2bf(xt##b_) << 16);
    PK(0, 0, 1)  PK(1, 2, 3)  PK(2, 4, 5)   PK(3, 6, 7)
    PK(4, 8, 9)  PK(5, 10, 11) PK(6, 12, 13) PK(7, 14, 15)
#undef PK
    {
        const u32x4v lo = {w0, w1, w2, w3};
        const u32x4v hi = {w4, w5, w6, w7};
        const int F = tid >> 5, c = tid & 31;
        sxt4[F * 64 + c]      = lo;
        sxt4[F * 64 + 32 + c] = hi;
    }
    __syncthreads();

    // ones-column B fragment for the -u init MFMA: B1[k][n] = (k==0)
    bf16x8 b1 = {0,0,0,0,0,0,0,0};
    if (lane < 32) b1[0] = (short)0x3F80;
    const bool h = (lane >= 32);

    float nll = 0.f;

#define PAIR(AV, AU, SA, SB) { \
    f32x16 acc = {}; \
    acc = __builtin_amdgcn_mfma_f32_32x32x16_bf16(AU, b1, acc, 0, 0, 0); \
    acc = __builtin_amdgcn_mfma_f32_32x32x16_bf16(AV, bx, acc, 0, 0, 0); \
    float sa = acc[0] * acc[0];    float sb = acc[8] * acc[8]; \
    sa = fmaf(acc[1], acc[1], sa); sb = fmaf(acc[9],  acc[9],  sb); \
    sa = fmaf(acc[2], acc[2], sa); sb = fmaf(acc[10], acc[10], sb); \
    sa = fmaf(acc[3], acc[3], sa); sb = fmaf(acc[11], acc[11], sb); \
    sa = fmaf(acc[4], acc[4], sa); sb = fmaf(acc[12], acc[12], sb); \
    sa = fmaf(acc[5], acc[5], sa); sb = fmaf(acc[13], acc[13], sb); \
    sa = fmaf(acc[6], acc[6], sa); sb = fmaf(acc[14], acc[14], sb); \
    sa = fmaf(acc[7], acc[7], sa); sb = fmaf(acc[15], acc[15], sb); \
    SA = sa; SB = sb; }

#define TILE(t_) { \
    const bf16x8 bx = __builtin_bit_cast(bf16x8, sxt4[(wid * 2 + t_) * 64 + lane]); \
    const float jn = __shfl(jac, t_ * 32 + (lane & 31), 64); \
    float pa0, pa1, pa2, pa3, pb0, pb1, pb2, pb3; \
    PAIR(av0, au0, pa0, pb0) PAIR(av1, au1, pa1, pb1) \
    PAIR(av2, au2, pa2, pb2) PAIR_DUMMY \
    PAIR(av3, au3, pa3, pb3) \
    const float k0 = h ? pa2 : pa0, s0 = h ? pa0 : pa2; \
    const float k1 = h ? pb2 : pb0, s1 = h ? pb0 : pb2; \
    const float k2 = h ? pa3 : pa1, s2 = h ? pa1 : pa3; \
    const float k3 = h ? pb3 : pb1, s3 = h ? pb1 : pb3; \
    float m = 0.f; \
    { const float q = k0 + __shfl_xor(s0, 32, 64); m += __expf(fmaf(-0.5f, q, (h ? ws[WS_LC + 4] : ws[WS_LC + 0]) + jn)); } \
    { const float q = k1 + __shfl_xor(s1, 32, 64); m += __expf(fmaf(-0.5f, q, (h ? ws[WS_LC + 5] : ws[WS_LC + 1]) + jn)); } \
    { const float q = k2 + __shfl_xor(s2, 32, 64); m += __expf(fmaf(-0.5f, q, (h ? ws[WS_LC + 6] : ws[WS_LC + 2]) + jn)); } \
    { const float q = k3 + __shfl_xor(s3, 32, 64); m += __expf(fmaf(-0.5f, q, (h ? ws[WS_LC + 7] : ws[WS_LC + 3]) + jn)); } \
    m += __shfl_xor(m, 32, 64); \
    const int drow = blockIdx.x * 256 + wid * 64 + t_ * 32 + (lane & 31); \
    if (!h && drow < nrows) nll -= __logf(m); }
#define PAIR_DUMMY

    TILE(0)
    TILE(1)
#undef TILE
#undef PAIR
#undef PAIR_DUMMY

#pragma unroll
    for (int off = 32; off > 0; off >>= 1) nll += __shfl_down(nll, off, 64);
    if (lane == 0) red[wid] = nll;
    __syncthreads();
    if (tid == 0) atomicAdd(out, red[0] + red[1] + red[2] + red[3]);
}

extern "C" void kernel_launch(void* const* d_in, const int* in_sizes, int n_in,
                              void* d_out, int out_size, void* d_ws, size_t ws_size,
                              hipStream_t stream) {
    const float* X       = (const float*)d_in[0];
    const float* lambdas = (const float*)d_in[1];
    const float* mus     = (const float*)d_in[2];
    const float* sigmas  = (const float*)d_in[3];
    const float* w       = (const float*)d_in[4];
    float* out = (float*)d_out;
    float* ws  = (float*)d_ws;

    const int nrows = in_sizes[0] / P;   // 524288

    gmm_prep<<<1, 128, 0, stream>>>(lambdas, mus, sigmas, w, ws, out);
    gmm_main<<<(nrows + 255) / 256, 256, 0, stream>>>(X, ws, out, nrows);
}

// Round 7
// 97.332 us; speedup vs baseline: 1.2159x; 1.2159x over previous
//
#include <hip/hip_runtime.h>
#include <hip/hip_bf16.h>

// GMM NLL: N=524288 rows, P=16, G=8.
// R7: kill the single-address atomicAdd (prime suspect for the universal
//   ~40-50us plateau: 2048 same-line device-scope atomics from 8 XCDs
//   serialize at the LLC ~15-25ns each = 30-50us, waves pinned in
//   s_waitcnt vmcnt(0) -> all pipes idle, occupancy ~37% -- matches every
//   round's counters). Blocks now write per-block partials (plain store);
//   a tiny third kernel reduces 2048 floats and writes out[0].
//   Also: prep rewritten fully-unrolled LDS-only (~4us instead of 15-20).
//   Main quad body = R6 (32x32x16 MFMA, named scalars; passed, absmax 0).

#define P 16
#define G 8

typedef short bf16x8 __attribute__((ext_vector_type(8)));
typedef unsigned u32x4v __attribute__((ext_vector_type(4)));
typedef float f32x16 __attribute__((ext_vector_type(16)));

__device__ __forceinline__ unsigned short f2bf(float f) {
    unsigned u = __builtin_bit_cast(unsigned, f);
    return (unsigned short)((u + 0x7FFFu + ((u >> 16) & 1u)) >> 16);  // RNE
}

// ws float-offset layout:
//   [0,1024)    A-frags: ushort[4 pairs][64 lanes][8]  (4 KB)
//   [1024,1280) u-frags: uint[4 pairs][64 lanes] (low16 = bf16(-u) for lane<32 else 0)
//   [1280,1288) lcoef[G]
//   [1288,...)  lam[P], lam-1[P], 1/lam[P]
//   [4096,6144) per-block partials (2048 floats)
#define UFRAG_F 1024
#define WS_LC   1280
#define WS_LAM  1288
#define WS_LM1  1304
#define WS_RL   1320
#define WS_PART 4096

__global__ __launch_bounds__(128) void gmm_prep(const float* __restrict__ lambdas,
                                                const float* __restrict__ mus,
                                                const float* __restrict__ sigmas,
                                                const float* __restrict__ w,
                                                float* __restrict__ ws) {
    __shared__ float Ssh[G][P][P];
    __shared__ float Lsh[G][P][P];
    __shared__ float Vsh[G][P][P];
    __shared__ float u_sh[G][P];
    __shared__ float ldet[G];
    const int tid = threadIdx.x;
    const int g = tid >> 4;
    const int r = tid & 15;

    // load Sigma rows (vectorized)
    {
        const float4* src = (const float4*)(sigmas + g * P * P + r * P);
        float4* dst = (float4*)&Ssh[g][r][0];
        dst[0] = src[0]; dst[1] = src[1]; dst[2] = src[2]; dst[3] = src[3];
    }
    __syncthreads();

    // left-looking Cholesky, fully unrolled; 2 barriers per column.
#pragma unroll
    for (int j = 0; j < P; ++j) {
        float s = Ssh[g][r][j];
#pragma unroll
        for (int k = 0; k < j; ++k) s -= Lsh[g][r][k] * Lsh[g][j][k];
        if (r == j) Lsh[g][j][j] = sqrtf(s);
        __syncthreads();
        if (r > j) Lsh[g][r][j] = s / Lsh[g][j][j];
        __syncthreads();
    }

    if (r == 0) {
        float ld = 0.f;
#pragma unroll
        for (int j = 0; j < P; ++j) ld += __logf(Lsh[g][j][j]);
        ldet[g] = 2.0f * ld;
    }

    // V = L^{-1}, column r per thread; zero-trick makes inner loop
    // compile-time (entries above diagonal are written as 0 and contribute 0).
#pragma unroll
    for (int i = 0; i < P; ++i) {
        float s = 0.f;
#pragma unroll
        for (int k = 0; k < i; ++k) s += Lsh[g][i][k] * Vsh[g][k][r];
        const float rii = 1.0f / Lsh[g][i][i];
        Vsh[g][i][r] = (i == r) ? rii : ((i < r) ? 0.f : -s * rii);
    }
    __syncthreads();

    // u_g[r] = (V_g mu_g)[r]
    {
        float u = 0.f;
#pragma unroll
        for (int j = 0; j < P; ++j) u = fmaf(Vsh[g][r][j], mus[g * P + j], u);
        u_sh[g][r] = u;
    }
    __syncthreads();

    // Fragment tables for mfma_f32_32x32x16_bf16:
    //   A[m][k], m=lane&31, k=(lane>>5)*8+j. Pair p rows: m<16 -> grp 2p, else 2p+1.
    unsigned short* ws16 = (unsigned short*)ws;
    unsigned* wsu32 = (unsigned*)(ws + UFRAG_F);
#pragma unroll
    for (int pid = tid; pid < 256; pid += 128) {
        const int p = pid >> 6, ln = pid & 63;
        const int m = ln & 31, half = ln >> 5;
        const int grp = 2 * (pid >> 6) + (m >> 4), i = m & 15;
        unsigned short* dst = ws16 + (p * 64 + ln) * 8;
#pragma unroll
        for (int j = 0; j < 8; ++j) dst[j] = f2bf(Vsh[grp][i][half * 8 + j]);
        wsu32[p * 64 + ln] = (half == 0) ? (unsigned)f2bf(-u_sh[grp][i]) : 0u;
    }

    if (tid == 0) {
        float wm = w[0];
#pragma unroll
        for (int k = 1; k < G; ++k) wm = fmaxf(wm, w[k]);
        float s = 0.f;
#pragma unroll
        for (int k = 0; k < G; ++k) s += __expf(w[k] - wm);
        const float lse = wm + __logf(s);
        const float lead = -14.7030165f; // -0.5 * 16 * ln(2*pi)
#pragma unroll
        for (int k = 0; k < G; ++k)
            ws[WS_LC + k] = (w[k] - lse) + lead - 0.5f * ldet[k];
    }
    if (tid < P) {
        float lam = lambdas[tid];
        ws[WS_LAM + tid] = lam;
        ws[WS_LM1 + tid] = lam - 1.0f;
        ws[WS_RL  + tid] = 1.0f / lam;
    }
}

__global__ __launch_bounds__(256, 4) void gmm_main(const float* __restrict__ X,
                                                   const float* __restrict__ ws,
                                                   float* __restrict__ partials,
                                                   int nrows) {
    __shared__ u32x4v sxt4[512];   // 8 frag-slots x 64 entries x 16B = 8 KB
    __shared__ float red[4];

    const int tid  = threadIdx.x;
    const int lane = tid & 63;
    const int wid  = tid >> 6;
    const unsigned short* ws16 = (const unsigned short*)ws;
    const unsigned* wsu32 = (const unsigned*)(ws + UFRAG_F);

    // resident fragments: 4 named A-vectors + 4 named u-vectors
    const bf16x8 av0 = *(const bf16x8*)(ws16 + (0 * 64 + lane) * 8);
    const bf16x8 av1 = *(const bf16x8*)(ws16 + (1 * 64 + lane) * 8);
    const bf16x8 av2 = *(const bf16x8*)(ws16 + (2 * 64 + lane) * 8);
    const bf16x8 av3 = *(const bf16x8*)(ws16 + (3 * 64 + lane) * 8);
    bf16x8 au0 = {0,0,0,0,0,0,0,0}; au0[0] = (short)wsu32[0 * 64 + lane];
    bf16x8 au1 = {0,0,0,0,0,0,0,0}; au1[0] = (short)wsu32[1 * 64 + lane];
    bf16x8 au2 = {0,0,0,0,0,0,0,0}; au2[0] = (short)wsu32[2 * 64 + lane];
    bf16x8 au3 = {0,0,0,0,0,0,0,0}; au3[0] = (short)wsu32[3 * 64 + lane];

    const int row = blockIdx.x * 256 + tid;
    const int rc = row < nrows ? row : nrows - 1;
    const float4* Xv = (const float4*)(X + (size_t)rc * P);
    const float4 A0 = Xv[0], A1 = Xv[1], A2 = Xv[2], A3 = Xv[3];

    float jac = 0.f;
#define XTP(i, xv_) \
    const float ln##i = __logf(xv_); \
    const float xt##i = (__expf(ws[WS_LAM + i] * ln##i) - 1.0f) * ws[WS_RL + i]; \
    jac = fmaf(ln##i, ws[WS_LM1 + i], jac);
    XTP(0, A0.x)  XTP(1, A0.y)  XTP(2, A0.z)  XTP(3, A0.w)
    XTP(4, A1.x)  XTP(5, A1.y)  XTP(6, A1.z)  XTP(7, A1.w)
    XTP(8, A2.x)  XTP(9, A2.y)  XTP(10, A2.z) XTP(11, A2.w)
    XTP(12, A3.x) XTP(13, A3.y) XTP(14, A3.z) XTP(15, A3.w)
#undef XTP

#define PK(h_, a_, b_) const unsigned w##h_ = (unsigned)f2bf(xt##a_) | ((unsigned)f2bf(xt##b_) << 16);
    PK(0, 0, 1)  PK(1, 2, 3)   PK(2, 4, 5)   PK(3, 6, 7)
    PK(4, 8, 9)  PK(5, 10, 11) PK(6, 12, 13) PK(7, 14, 15)
#undef PK
    {
        const u32x4v lo = {w0, w1, w2, w3};
        const u32x4v hi = {w4, w5, w6, w7};
        const int F = tid >> 5, c = tid & 31;
        sxt4[F * 64 + c]      = lo;
        sxt4[F * 64 + 32 + c] = hi;
    }
    __syncthreads();

    // ones-column B fragment for the -u init MFMA: B1[k][n] = (k==0)
    bf16x8 b1 = {0,0,0,0,0,0,0,0};
    if (lane < 32) b1[0] = (short)0x3F80;
    const bool h = (lane >= 32);

    float nll = 0.f;

#define PAIR(AV, AU, SA, SB) { \
    f32x16 acc = {}; \
    acc = __builtin_amdgcn_mfma_f32_32x32x16_bf16(AU, b1, acc, 0, 0, 0); \
    acc = __builtin_amdgcn_mfma_f32_32x32x16_bf16(AV, bx, acc, 0, 0, 0); \
    float sa = acc[0] * acc[0];    float sb = acc[8] * acc[8]; \
    sa = fmaf(acc[1], acc[1], sa); sb = fmaf(acc[9],  acc[9],  sb); \
    sa = fmaf(acc[2], acc[2], sa); sb = fmaf(acc[10], acc[10], sb); \
    sa = fmaf(acc[3], acc[3], sa); sb = fmaf(acc[11], acc[11], sb); \
    sa = fmaf(acc[4], acc[4], sa); sb = fmaf(acc[12], acc[12], sb); \
    sa = fmaf(acc[5], acc[5], sa); sb = fmaf(acc[13], acc[13], sb); \
    sa = fmaf(acc[6], acc[6], sa); sb = fmaf(acc[14], acc[14], sb); \
    sa = fmaf(acc[7], acc[7], sa); sb = fmaf(acc[15], acc[15], sb); \
    SA = sa; SB = sb; }

#define TILE(t_) { \
    const bf16x8 bx = __builtin_bit_cast(bf16x8, sxt4[(wid * 2 + t_) * 64 + lane]); \
    const float jn = __shfl(jac, t_ * 32 + (lane & 31), 64); \
    float pa0, pa1, pa2, pa3, pb0, pb1, pb2, pb3; \
    PAIR(av0, au0, pa0, pb0) PAIR(av1, au1, pa1, pb1) \
    PAIR(av2, au2, pa2, pb2) PAIR(av3, au3, pa3, pb3) \
    const float k0 = h ? pa2 : pa0, s0 = h ? pa0 : pa2; \
    const float k1 = h ? pb2 : pb0, s1 = h ? pb0 : pb2; \
    const float k2 = h ? pa3 : pa1, s2 = h ? pa1 : pa3; \
    const float k3 = h ? pb3 : pb1, s3 = h ? pb1 : pb3; \
    float m = 0.f; \
    { const float q = k0 + __shfl_xor(s0, 32, 64); m += __expf(fmaf(-0.5f, q, (h ? ws[WS_LC + 4] : ws[WS_LC + 0]) + jn)); } \
    { const float q = k1 + __shfl_xor(s1, 32, 64); m += __expf(fmaf(-0.5f, q, (h ? ws[WS_LC + 5] : ws[WS_LC + 1]) + jn)); } \
    { const float q = k2 + __shfl_xor(s2, 32, 64); m += __expf(fmaf(-0.5f, q, (h ? ws[WS_LC + 6] : ws[WS_LC + 2]) + jn)); } \
    { const float q = k3 + __shfl_xor(s3, 32, 64); m += __expf(fmaf(-0.5f, q, (h ? ws[WS_LC + 7] : ws[WS_LC + 3]) + jn)); } \
    m += __shfl_xor(m, 32, 64); \
    const int drow = blockIdx.x * 256 + wid * 64 + t_ * 32 + (lane & 31); \
    if (!h && drow < nrows) nll -= __logf(m); }

    TILE(0)
    TILE(1)
#undef TILE
#undef PAIR

#pragma unroll
    for (int off = 32; off > 0; off >>= 1) nll += __shfl_down(nll, off, 64);
    if (lane == 0) red[wid] = nll;
    __syncthreads();
    // plain per-block store -- NO same-address atomic
    if (tid == 0) partials[blockIdx.x] = red[0] + red[1] + red[2] + red[3];
}

__global__ __launch_bounds__(256) void gmm_reduce(const float* __restrict__ partials,
                                                  float* __restrict__ out, int n) {
    __shared__ float red[4];
    const int tid = threadIdx.x;
    float s = 0.f;
    for (int i = tid; i < n; i += 256) s += partials[i];
#pragma unroll
    for (int off = 32; off > 0; off >>= 1) s += __shfl_down(s, off, 64);
    if ((tid & 63) == 0) red[tid >> 6] = s;
    __syncthreads();
    if (tid == 0) out[0] = red[0] + red[1] + red[2] + red[3];
}

extern "C" void kernel_launch(void* const* d_in, const int* in_sizes, int n_in,
                              void* d_out, int out_size, void* d_ws, size_t ws_size,
                              hipStream_t stream) {
    const float* X       = (const float*)d_in[0];
    const float* lambdas = (const float*)d_in[1];
    const float* mus     = (const float*)d_in[2];
    const float* sigmas  = (const float*)d_in[3];
    const float* w       = (const float*)d_in[4];
    float* out = (float*)d_out;
    float* ws  = (float*)d_ws;

    const int nrows = in_sizes[0] / P;   // 524288
    const int nblocks = (nrows + 255) / 256;  // 2048

    gmm_prep<<<1, 128, 0, stream>>>(lambdas, mus, sigmas, w, ws);
    gmm_main<<<nblocks, 256, 0, stream>>>(X, ws, ws + WS_PART, nrows);
    gmm_reduce<<<1, 256, 0, stream>>>(ws + WS_PART, out, nblocks);
}